// Round 8
// baseline (29165.189 us; speedup 1.0000x reference)
//
#include <hip/hip_runtime.h>
#include <hip/hip_fp16.h>

typedef unsigned int u32;
typedef _Float16 h2v __attribute__((ext_vector_type(2)));

#define TSLEN 512
#define N0 306
#define N1 204
#define D0 370
#define D1 510
#define D2 206
#define RPB 4            // rows per block

// ws u32/f32 offsets (identical to round-7 verified layout)
#define OFF_WA  0          // uint4[48][918]  layer-A planes (plane-major, lane-coalesced)
#define OFF_WB  176256     // uint4[48][816]  layer-B planes
#define OFF_WC1 332928     // f32[2][208]
#define OFF_WC2 333344
#define OFF_WCT 333760
#define OFF_BA  334176     // float4[306]
#define OFF_BB  335400     // float4[204]
#define OFF_B2  336216     // float4[2]

__device__ __forceinline__ u32 packh2(float a, float b) {
  __half2 h = __floats2half2_rn(a, b);
  return __builtin_bit_cast(u32, h);
}

__device__ __forceinline__ float dot2(u32 w, u32 xx, float acc) {
  return __builtin_amdgcn_fdot2(__builtin_bit_cast(h2v, w), __builtin_bit_cast(h2v, xx), acc, false);
}

__device__ __forceinline__ float cellact3(float a1, float a2, float at, float4 b) {
  float t1 = tanhf(a1 + b.x);
  float t2 = tanhf(a2 + b.y);
  float tv = 1.f / (1.f + __expf(-(at + b.z)));   // sigmoid(tb - ta)
  return t1 * (1.f - tv) + tv * t2;
}

__global__ __launch_bounds__(256) void prep_kernel(
    const float* __restrict__ f1w0, const float* __restrict__ f2w0,
    const float* __restrict__ taw0, const float* __restrict__ tbw0, const int* __restrict__ m0,
    const float* __restrict__ f1b0, const float* __restrict__ f2b0,
    const float* __restrict__ tab0, const float* __restrict__ tbb0,
    const float* __restrict__ f1w1, const float* __restrict__ f2w1,
    const float* __restrict__ taw1, const float* __restrict__ tbw1, const int* __restrict__ m1,
    const float* __restrict__ f1b1, const float* __restrict__ f2b1,
    const float* __restrict__ tab1, const float* __restrict__ tbb1,
    const float* __restrict__ f1w2, const float* __restrict__ f2w2,
    const float* __restrict__ taw2, const float* __restrict__ tbw2, const int* __restrict__ m2,
    const float* __restrict__ f1b2, const float* __restrict__ f2b2,
    const float* __restrict__ tab2, const float* __restrict__ tbb2,
    float* __restrict__ ws)
{
  int j = blockIdx.x * 256 + threadIdx.x;
  u32* W = (u32*)ws;
  if (j < 176256) {                       // layer A: [plane*16+jj][u*3+s] uint4, component c
    int q4 = j >> 2, c = j & 3;
    int jq = q4 / 918, us = q4 - jq * 918;
    int u = us / 3, s = us - u * 3;
    int plane = jq >> 4, jj = jq & 15;
    int p = s * 64 + jj * 4 + c;          // k-pair index in padded 384-k space
    int k0 = 2 * p, k1 = 2 * p + 1;
    float v0 = 0.f, v1 = 0.f;
    if (k0 < D0) {
      int i = u * D0 + k0;
      v0 = (plane == 0) ? f1w0[i] * (float)m0[i]
         : (plane == 1) ? f2w0[i] * (float)m0[i]
                        : tbw0[i] - taw0[i];
    }
    if (k1 < D0) {
      int i = u * D0 + k1;
      v1 = (plane == 0) ? f1w0[i] * (float)m0[i]
         : (plane == 1) ? f2w0[i] * (float)m0[i]
                        : tbw0[i] - taw0[i];
    }
    W[OFF_WA + j] = packh2(v0, v1);
    return;
  }
  j -= 176256;
  if (j < 156672) {                       // layer B: [plane*16+jj][u*4+s]
    int q4 = j >> 2, c = j & 3;
    int jq = q4 / 816, us = q4 - jq * 816;
    int u = us >> 2, s = us & 3;
    int plane = jq >> 4, jj = jq & 15;
    int p = s * 64 + jj * 4 + c;          // padded 512-k space
    int k0 = 2 * p, k1 = 2 * p + 1;
    float v0 = 0.f, v1 = 0.f;
    if (k0 < D1) {
      int i = u * D1 + k0;
      v0 = (plane == 0) ? f1w1[i] * (float)m1[i]
         : (plane == 1) ? f2w1[i] * (float)m1[i]
                        : tbw1[i] - taw1[i];
    }
    if (k1 < D1) {
      int i = u * D1 + k1;
      v1 = (plane == 0) ? f1w1[i] * (float)m1[i]
         : (plane == 1) ? f2w1[i] * (float)m1[i]
                        : tbw1[i] - taw1[i];
    }
    W[OFF_WB + j] = packh2(v0, v1);
    return;
  }
  j -= 156672;
  if (j < 416) {                          // layer C (fp32 [u][208])
    int u = j / 208, d = j - u * 208;
    float f1 = 0.f, f2 = 0.f, td = 0.f;
    if (d < D2) { int i = u * D2 + d; float m = (float)m2[i]; f1 = f1w2[i]*m; f2 = f2w2[i]*m; td = tbw2[i]-taw2[i]; }
    ws[OFF_WC1 + j] = f1; ws[OFF_WC2 + j] = f2; ws[OFF_WCT + j] = td;
    return;
  }
  j -= 416;
  if (j < 306) { ((float4*)(ws + OFF_BA))[j] = make_float4(f1b0[j], f2b0[j], tbb0[j] - tab0[j], 0.f); return; }
  j -= 306;
  if (j < 204) { ((float4*)(ws + OFF_BB))[j] = make_float4(f1b1[j], f2b1[j], tbb1[j] - tab1[j], 0.f); return; }
  j -= 204;
  if (j < 2)   { ((float4*)(ws + OFF_B2))[j] = make_float4(f1b2[j], f2b2[j], tbb2[j] - tab2[j], 0.f); return; }
}

// One block = RPB(4) batch rows. Weight uint4 loaded once, used for 4 rows.
// x/state in LDS (half2, wave-broadcast reads); partial sums via LDS.
__global__ __launch_bounds__(1024, 1) void lnn_main(
    const float* __restrict__ x, const float* __restrict__ h0,
    const float* __restrict__ fcw, const float* __restrict__ fcb,
    const float* __restrict__ ws, float* __restrict__ out)
{
  __shared__ uint4 XA4[RPB][48];      // [x(64)|hi(306)|pad] as half2
  __shared__ uint4 XB4[RPB][64];      // [hi(306)|hc(204)|pad] as half2
  __shared__ float XB32[RPB][512];    // f32: hi(306) | hc(204) | pad(2)
  __shared__ float pA[RPB][2754];     // 918*3 partials
  __shared__ float pB[RPB][2652];     // 204*13 partials
  __shared__ float4 sBA[306];
  __shared__ float4 sBB[204];
  __shared__ float shm_hm[RPB][2];

  const int tid = threadIdx.x;
  const int row0 = blockIdx.x * RPB;

  const int sA3 = tid % 3;                  // A: tid = u*3 + s (tid < 918)
  const int sB4 = tid & 3;                  // B: tid = u*4 + s (tid < 816)

  const uint4* __restrict__ WA4 = (const uint4*)((const u32*)ws + OFF_WA);
  const uint4* __restrict__ WB4 = (const uint4*)((const u32*)ws + OFF_WB);

  __half* XAh = (__half*)&XA4[0][0];        // flat [r*768 + idx] layout? no: per-row pointers below
  // per-row half pointers
  // XA row r: (__half*)XA4[r] ; XB row r: (__half*)XB4[r]

  // ---- wave-15 (layer C) persistent state ----
  const int l15 = tid - 960;
  const int u2 = l15 & 1, r2c = (l15 >> 1) & 3, chc = l15 >> 3;   // valid for tid>=960
  float4 b2 = make_float4(0.f, 0.f, 0.f, 0.f);
  float hm0 = 0.f, hm1 = 0.f;
  if (tid >= 960) {
    b2 = ((const float4*)(ws + OFF_B2))[u2];
    hm0 = h0[(size_t)(row0 + r2c) * 512 + 510];
    hm1 = h0[(size_t)(row0 + r2c) * 512 + 511];
  }

  // ---- init LDS ----
  if (tid < 306) sBA[tid] = ((const float4*)(ws + OFF_BA))[tid];
  if (tid < 204) sBB[tid] = ((const float4*)(ws + OFF_BB))[tid];
  for (int i = tid; i < RPB * N0; i += 1024) {       // hi init (XAh region)
    int u = i >> 2, r = i & 3;
    ((__half*)XA4[r])[64 + u] = __float2half(h0[(size_t)(row0 + r) * 512 + u]);
  }
  for (int i = tid; i < RPB * N1; i += 1024) {       // hc init (XBh region)
    int u = i >> 2, r = i & 3;
    ((__half*)XB4[r])[306 + u] = __float2half(h0[(size_t)(row0 + r) * 512 + 306 + u]);
  }
  if (tid < RPB * 14) {                              // XA pad k=370..383
    int r = tid / 14, u = tid - r * 14;
    ((__half*)XA4[r])[370 + u] = __float2half(0.f);
  }
  if (tid >= 64 && tid < 64 + RPB * 2) {             // XB pad k=510..511
    int i = tid - 64; int r = i >> 1;
    ((__half*)XB4[r])[510 + (i & 1)] = __float2half(0.f);
  }
  __syncthreads();

  for (int t = 0; t < TSLEN; ++t) {
    // ---- phase 1: B-finish(t-1) [tid<816]; x_t staging [816..943] ----
    if (tid < 816) {
      if (t > 0) {
        int u = tid >> 2, r = tid & 3;
        const float* b = &pB[r][u * 13];
        float a1 = b[0] + b[3] + b[6] + b[9];
        float a2 = b[1] + b[4] + b[7] + b[10];
        float at = b[2] + b[5] + b[8] + b[11];
        float hc = cellact3(a1, a2, at, sBB[u]);
        XB32[r][306 + u] = hc;
        ((__half*)XB4[r])[306 + u] = __float2half(hc);
      }
    } else if (tid < 944) {
      int i = tid - 816;                  // 0..127: 4 rows x 32 packs
      int r = i >> 5, jj = i & 31;
      float2 xv = *(const float2*)(x + ((size_t)(row0 + r) * TSLEN + t) * 64 + 2 * jj);
      ((u32*)XA4[r])[jj] = packh2(xv.x, xv.y);
    }
    __syncthreads();

    // ---- phase 2: A-partials [tid<918] + lagged layer C [wave 15] ----
    if (tid < 918) {
      const uint4* wp = WA4 + tid;
      float acc[3][RPB];
      #pragma unroll
      for (int p = 0; p < 3; ++p)
        #pragma unroll
        for (int r = 0; r < RPB; ++r) acc[p][r] = 0.f;
      #pragma unroll
      for (int h = 0; h < 2; ++h) {
        #pragma unroll
        for (int p = 0; p < 3; ++p) {
          uint4 wv[8];
          #pragma unroll
          for (int j = 0; j < 8; ++j) wv[j] = wp[(p * 16 + h * 8 + j) * 918];
          #pragma unroll
          for (int r = 0; r < RPB; ++r) {
            const uint4* xs = &XA4[r][sA3 * 16 + h * 8];
            #pragma unroll
            for (int j = 0; j < 8; ++j) {
              uint4 xq = xs[j];
              acc[p][r] = dot2(wv[j].x, xq.x, acc[p][r]);
              acc[p][r] = dot2(wv[j].y, xq.y, acc[p][r]);
              acc[p][r] = dot2(wv[j].z, xq.z, acc[p][r]);
              acc[p][r] = dot2(wv[j].w, xq.w, acc[p][r]);
            }
          }
        }
      }
      #pragma unroll
      for (int r = 0; r < RPB; ++r) {
        pA[r][tid * 3 + 0] = acc[0][r];
        pA[r][tid * 3 + 1] = acc[1][r];
        pA[r][tid * 3 + 2] = acc[2][r];
      }
    } else if (tid >= 960 && t > 0) {
      // hm(t-1) = cell2([hc(t-1), hm(t-2)]) ; hc(t-1) in XB32[.][306..509]
      float a1 = 0.f, a2 = 0.f, at = 0.f;
      int dbase = chc * 26;
      #pragma unroll
      for (int j = 0; j < 26; ++j) {
        int d = dbase + j;
        float w1 = ws[OFF_WC1 + u2 * 208 + d];
        float w2 = ws[OFF_WC2 + u2 * 208 + d];
        float wt = ws[OFF_WCT + u2 * 208 + d];
        float xv = (d < 204) ? XB32[r2c][306 + d] : (d == 204 ? hm0 : (d == 205 ? hm1 : 0.f));
        a1 = fmaf(w1, xv, a1); a2 = fmaf(w2, xv, a2); at = fmaf(wt, xv, at);
      }
      a1 += __shfl_xor(a1, 8);  a2 += __shfl_xor(a2, 8);  at += __shfl_xor(at, 8);
      a1 += __shfl_xor(a1, 16); a2 += __shfl_xor(a2, 16); at += __shfl_xor(at, 16);
      a1 += __shfl_xor(a1, 32); a2 += __shfl_xor(a2, 32); at += __shfl_xor(at, 32);
      float hmn = cellact3(a1, a2, at, b2);
      float other = __shfl_xor(hmn, 1);
      hm0 = (u2 == 0) ? hmn : other;
      hm1 = (u2 == 0) ? other : hmn;
    }
    __syncthreads();

    // ---- phase 3: A-finish -> hi(t), 1224 items ----
    for (int i = tid; i < RPB * N0; i += 1024) {
      int u = i >> 2, r = i & 3;
      const float* b = &pA[r][u * 9];
      float a1 = b[0] + b[3] + b[6];
      float a2 = b[1] + b[4] + b[7];
      float at = b[2] + b[5] + b[8];
      float hi = cellact3(a1, a2, at, sBA[u]);
      XB32[r][u] = hi;
      __half hh = __float2half(hi);
      ((__half*)XB4[r])[u] = hh;
      ((__half*)XA4[r])[64 + u] = hh;
    }
    __syncthreads();

    // ---- phase 4: B-partials [tid<816] ----
    if (tid < 816) {
      const uint4* wp = WB4 + tid;
      int ub = tid >> 2;
      float acc[3][RPB];
      #pragma unroll
      for (int p = 0; p < 3; ++p)
        #pragma unroll
        for (int r = 0; r < RPB; ++r) acc[p][r] = 0.f;
      #pragma unroll
      for (int h = 0; h < 2; ++h) {
        #pragma unroll
        for (int p = 0; p < 3; ++p) {
          uint4 wv[8];
          #pragma unroll
          for (int j = 0; j < 8; ++j) wv[j] = wp[(p * 16 + h * 8 + j) * 816];
          #pragma unroll
          for (int r = 0; r < RPB; ++r) {
            const uint4* xs = &XB4[r][sB4 * 16 + h * 8];
            #pragma unroll
            for (int j = 0; j < 8; ++j) {
              uint4 xq = xs[j];
              acc[p][r] = dot2(wv[j].x, xq.x, acc[p][r]);
              acc[p][r] = dot2(wv[j].y, xq.y, acc[p][r]);
              acc[p][r] = dot2(wv[j].z, xq.z, acc[p][r]);
              acc[p][r] = dot2(wv[j].w, xq.w, acc[p][r]);
            }
          }
        }
      }
      #pragma unroll
      for (int r = 0; r < RPB; ++r) {
        pB[r][ub * 13 + sB4 * 3 + 0] = acc[0][r];
        pB[r][ub * 13 + sB4 * 3 + 1] = acc[1][r];
        pB[r][ub * 13 + sB4 * 3 + 2] = acc[2][r];
      }
    }
    __syncthreads();
  }

  // ---- epilogue: B-finish t=511 -> hc(511) ----
  if (tid < 816) {
    int u = tid >> 2, r = tid & 3;
    const float* b = &pB[r][u * 13];
    float a1 = b[0] + b[3] + b[6] + b[9];
    float a2 = b[1] + b[4] + b[7] + b[10];
    float at = b[2] + b[5] + b[8] + b[11];
    XB32[r][306 + u] = cellact3(a1, a2, at, sBB[u]);
  }
  __syncthreads();
  if (tid >= 960) {  // hm(511) from hc(511) + hm(510)
    float a1 = 0.f, a2 = 0.f, at = 0.f;
    int dbase = chc * 26;
    #pragma unroll
    for (int j = 0; j < 26; ++j) {
      int d = dbase + j;
      float w1 = ws[OFF_WC1 + u2 * 208 + d];
      float w2 = ws[OFF_WC2 + u2 * 208 + d];
      float wt = ws[OFF_WCT + u2 * 208 + d];
      float xv = (d < 204) ? XB32[r2c][306 + d] : (d == 204 ? hm0 : (d == 205 ? hm1 : 0.f));
      a1 = fmaf(w1, xv, a1); a2 = fmaf(w2, xv, a2); at = fmaf(wt, xv, at);
    }
    a1 += __shfl_xor(a1, 8);  a2 += __shfl_xor(a2, 8);  at += __shfl_xor(at, 8);
    a1 += __shfl_xor(a1, 16); a2 += __shfl_xor(a2, 16); at += __shfl_xor(at, 16);
    a1 += __shfl_xor(a1, 32); a2 += __shfl_xor(a2, 32); at += __shfl_xor(at, 32);
    float hmn = cellact3(a1, a2, at, b2);
    if (chc == 0) shm_hm[r2c][u2] = hmn;
  }
  __syncthreads();

  if (tid < 2 * RPB) {
    int r = tid >> 1, o = tid & 1;
    out[(size_t)(row0 + r) * 2 + o] =
        shm_hm[r][0] * fcw[o * 2 + 0] + shm_hm[r][1] * fcw[o * 2 + 1] + fcb[o];
  }
  for (int i = tid; i < RPB * 512; i += 1024) {
    int r = i >> 9, c = i & 511;
    float v = (c < 510) ? XB32[r][c] : shm_hm[r][c - 510];
    out[512 + (size_t)(row0 + r) * 512 + c] = v;
  }
}

extern "C" void kernel_launch(void* const* d_in, const int* in_sizes, int n_in,
                              void* d_out, int out_size, void* d_ws, size_t ws_size,
                              hipStream_t stream) {
  const float* x    = (const float*)d_in[0];
  const float* h0   = (const float*)d_in[1];
  const float* f1w0 = (const float*)d_in[2];
  const float* f1b0 = (const float*)d_in[3];
  const float* f2w0 = (const float*)d_in[4];
  const float* f2b0 = (const float*)d_in[5];
  const float* taw0 = (const float*)d_in[6];
  const float* tab0 = (const float*)d_in[7];
  const float* tbw0 = (const float*)d_in[8];
  const float* tbb0 = (const float*)d_in[9];
  const int*   m0   = (const int*)d_in[10];
  const float* f1w1 = (const float*)d_in[11];
  const float* f1b1 = (const float*)d_in[12];
  const float* f2w1 = (const float*)d_in[13];
  const float* f2b1 = (const float*)d_in[14];
  const float* taw1 = (const float*)d_in[15];
  const float* tab1 = (const float*)d_in[16];
  const float* tbw1 = (const float*)d_in[17];
  const float* tbb1 = (const float*)d_in[18];
  const int*   m1   = (const int*)d_in[19];
  const float* f1w2 = (const float*)d_in[20];
  const float* f1b2 = (const float*)d_in[21];
  const float* f2w2 = (const float*)d_in[22];
  const float* f2b2 = (const float*)d_in[23];
  const float* taw2 = (const float*)d_in[24];
  const float* tab2 = (const float*)d_in[25];
  const float* tbw2 = (const float*)d_in[26];
  const float* tbb2 = (const float*)d_in[27];
  const int*   m2   = (const int*)d_in[28];
  const float* fcw  = (const float*)d_in[29];
  const float* fcb  = (const float*)d_in[30];

  float* ws  = (float*)d_ws;
  float* out = (float*)d_out;

  prep_kernel<<<1305, 256, 0, stream>>>(
      f1w0, f2w0, taw0, tbw0, m0, f1b0, f2b0, tab0, tbb0,
      f1w1, f2w1, taw1, tbw1, m1, f1b1, f2b1, tab1, tbb1,
      f1w2, f2w2, taw2, tbw2, m2, f1b2, f2b2, tab2, tbb2,
      ws);

  lnn_main<<<64, 1024, 0, stream>>>(x, h0, fcw, fcb, ws, out);
}

// Round 9
// 28698.639 us; speedup vs baseline: 1.0163x; 1.0163x over previous
//
#include <hip/hip_runtime.h>
#include <hip/hip_fp16.h>

typedef unsigned int u32;
typedef _Float16 h2v __attribute__((ext_vector_type(2)));

#define TSLEN 512
#define N0 306
#define N1 204
#define D0 370
#define D1 510
#define D2 206
#define NSL 16      // unit-slices per group
#define RPG 16      // rows per group

// ws dword offsets
#define OFF_WAG 0                       // uint4[16][20][3][48] = 184320 dw
#define OFF_WBG 184320                  // uint4[16][13][3][64] = 159744 dw
#define OFF_WC1 344064                  // f32[2][208]
#define OFF_WC2 344480
#define OFF_WCT 344896
#define OFF_BA  345312                  // float4[306]
#define OFF_BB  346536                  // float4[204]
#define OFF_B2  347352                  // float4[2]
#define OFF_HIB 347360                  // f32[2][256][306]
#define OFF_HCB 504032                  // f32[2][256][204]
#define OFF_FLG 608480                  // int[16][16]

__device__ __forceinline__ u32 packh2(float a, float b) {
  __half2 h = __floats2half2_rn(a, b);
  return __builtin_bit_cast(u32, h);
}
__device__ __forceinline__ float dot2(u32 w, u32 xx, float acc) {
  return __builtin_amdgcn_fdot2(__builtin_bit_cast(h2v, w), __builtin_bit_cast(h2v, xx), acc, false);
}
__device__ __forceinline__ float cellact3(float a1, float a2, float at, float4 b) {
  float t1 = tanhf(a1 + b.x);
  float t2 = tanhf(a2 + b.y);
  float tv = 1.f / (1.f + __expf(-(at + b.z)));
  return t1 * (1.f - tv) + tv * t2;
}
__device__ __forceinline__ void dot3p(uint4 w0, uint4 w1, uint4 w2, uint4 xq,
                                      float& a0, float& a1, float& a2) {
  a0 = dot2(w0.x, xq.x, a0); a0 = dot2(w0.y, xq.y, a0); a0 = dot2(w0.z, xq.z, a0); a0 = dot2(w0.w, xq.w, a0);
  a1 = dot2(w1.x, xq.x, a1); a1 = dot2(w1.y, xq.y, a1); a1 = dot2(w1.z, xq.z, a1); a1 = dot2(w1.w, xq.w, a1);
  a2 = dot2(w2.x, xq.x, a2); a2 = dot2(w2.y, xq.y, a2); a2 = dot2(w2.z, xq.z, a2); a2 = dot2(w2.w, xq.w, a2);
}

__global__ __launch_bounds__(256) void prep_kernel(
    const float* __restrict__ h0,
    const float* __restrict__ f1w0, const float* __restrict__ f2w0,
    const float* __restrict__ taw0, const float* __restrict__ tbw0, const int* __restrict__ m0,
    const float* __restrict__ f1b0, const float* __restrict__ f2b0,
    const float* __restrict__ tab0, const float* __restrict__ tbb0,
    const float* __restrict__ f1w1, const float* __restrict__ f2w1,
    const float* __restrict__ taw1, const float* __restrict__ tbw1, const int* __restrict__ m1,
    const float* __restrict__ f1b1, const float* __restrict__ f2b1,
    const float* __restrict__ tab1, const float* __restrict__ tbb1,
    const float* __restrict__ f1w2, const float* __restrict__ f2w2,
    const float* __restrict__ taw2, const float* __restrict__ tbw2, const int* __restrict__ m2,
    const float* __restrict__ f1b2, const float* __restrict__ f2b2,
    const float* __restrict__ tab2, const float* __restrict__ tbb2,
    float* __restrict__ ws)
{
  int j = blockIdx.x * 256 + threadIdx.x;
  u32* W = (u32*)ws;
  if (j < 184320) {                      // layer-A slices: [s][20][3][48] uint4
    int q = j >> 2, c = j & 3;
    int s = q / 2880, r1 = q - s * 2880;
    int ul = r1 / 144, r2 = r1 - ul * 144;
    int p = r2 / 48, k8 = r2 - p * 48;
    int k = k8 * 8 + c * 2;
    int nu = 19 + (s < 2);
    int u = s * 19 + (s < 2 ? s : 2) + ul;
    float v0 = 0.f, v1 = 0.f;
    if (ul < nu) {
      if (k < D0) {
        int i = u * D0 + k;
        v0 = (p == 0) ? f1w0[i] * (float)m0[i] : (p == 1) ? f2w0[i] * (float)m0[i] : tbw0[i] - taw0[i];
      }
      if (k + 1 < D0) {
        int i = u * D0 + k + 1;
        v1 = (p == 0) ? f1w0[i] * (float)m0[i] : (p == 1) ? f2w0[i] * (float)m0[i] : tbw0[i] - taw0[i];
      }
    }
    W[OFF_WAG + j] = packh2(v0, v1);
    return;
  }
  j -= 184320;
  if (j < 159744) {                      // layer-B slices: [s][13][3][64] uint4
    int q = j >> 2, c = j & 3;
    int s = q / 2496, r1 = q - s * 2496;
    int ul = r1 / 192, r2 = r1 - ul * 192;
    int p = r2 / 64, k8 = r2 - p * 64;
    int k = k8 * 8 + c * 2;
    int nu = 12 + (s < 12);
    int u = s * 12 + (s < 12 ? s : 12) + ul;
    float v0 = 0.f, v1 = 0.f;
    if (ul < nu) {
      if (k < D1) {
        int i = u * D1 + k;
        v0 = (p == 0) ? f1w1[i] * (float)m1[i] : (p == 1) ? f2w1[i] * (float)m1[i] : tbw1[i] - taw1[i];
      }
      if (k + 1 < D1) {
        int i = u * D1 + k + 1;
        v1 = (p == 0) ? f1w1[i] * (float)m1[i] : (p == 1) ? f2w1[i] * (float)m1[i] : tbw1[i] - taw1[i];
      }
    }
    W[OFF_WBG + j] = packh2(v0, v1);
    return;
  }
  j -= 159744;
  if (j < 1248) {                        // layer C planes fp32 [pl][2][208]
    int pl = j / 416, rest = j - pl * 416;
    int u2 = rest / 208, d = rest - u2 * 208;
    float v = 0.f;
    if (d < D2) {
      int i = u2 * D2 + d;
      v = (pl == 0) ? f1w2[i] * (float)m2[i] : (pl == 1) ? f2w2[i] * (float)m2[i] : tbw2[i] - taw2[i];
    }
    ws[OFF_WC1 + j] = v;
    return;
  }
  j -= 1248;
  if (j < 306) { *((float4*)(ws + OFF_BA) + j) = make_float4(f1b0[j], f2b0[j], tbb0[j] - tab0[j], 0.f); return; }
  j -= 306;
  if (j < 204) { *((float4*)(ws + OFF_BB) + j) = make_float4(f1b1[j], f2b1[j], tbb1[j] - tab1[j], 0.f); return; }
  j -= 204;
  if (j < 2)   { *((float4*)(ws + OFF_B2) + j) = make_float4(f1b2[j], f2b2[j], tbb2[j] - tab2[j], 0.f); return; }
  j -= 2;
  if (j < 256 * 306) {                   // hi_buf[1] = h0 hi
    int r = j / 306, u = j - r * 306;
    ws[OFF_HIB + 256 * 306 + j] = h0[(size_t)r * 512 + u];
    return;
  }
  j -= 256 * 306;
  if (j < 256 * 204) {                   // hc_buf[1] = h0 hc
    int r = j / 204, u = j - r * 204;
    ws[OFF_HCB + 256 * 204 + j] = h0[(size_t)r * 512 + 306 + u];
    return;
  }
  j -= 256 * 204;
  if (j < 256) { ((int*)(ws + OFF_FLG))[j] = 0; return; }
}

__device__ __forceinline__ void group_sync(int* flag, int target) {
  __syncthreads();    // all waves drain vmem (compiler emits vmcnt(0) before barrier)
  if (threadIdx.x == 0) {
    __hip_atomic_fetch_add(flag, 1, __ATOMIC_RELEASE, __HIP_MEMORY_SCOPE_AGENT);
    int spins = 0;
    while (__hip_atomic_load(flag, __ATOMIC_ACQUIRE, __HIP_MEMORY_SCOPE_AGENT) < target) {
      __builtin_amdgcn_s_sleep(4);
      if (++spins > 100000) break;   // fail-open: wrong answer beats a hang
    }
  }
  __syncthreads();
}

// 256 blocks = 16 row-groups x 16 unit-slices. Weights LDS-resident (staged once).
// Per step: 2 group-local (16-block, XCD-co-located) rendezvous via ws counters.
__global__ __launch_bounds__(512, 1) void lnn_main(
    const float* __restrict__ x, const float* __restrict__ h0,
    const float* __restrict__ fcw, const float* __restrict__ fcb,
    float* __restrict__ ws, float* __restrict__ out)
{
  extern __shared__ char smem[];
  uint4* WAl = (uint4*)smem;            // [20][145] = 2900
  uint4* WBl = WAl + 2900;              // [13][193] = 2509
  uint4* XA  = WBl + 2509;              // [16][49]
  uint4* XB  = XA + 784;                // [16][65]
  float* WC1l = (float*)(XB + 1040);    // 416
  float* WC2l = WC1l + 416;
  float* WCTl = WC2l + 416;
  float* hmloc = WCTl + 416;            // [2][16][2]

  const int tid = threadIdx.x;
  const int bid = blockIdx.x;
  const int w8 = bid >> 3;
  const int group = (bid & 7) * 2 + (w8 & 1);   // group-mates share bid%8 -> same XCD (heuristic)
  const int slice = w8 >> 1;
  const int rows0 = group * RPG;
  const int nu0 = 19 + (slice < 2);
  const int u0  = slice * 19 + (slice < 2 ? slice : 2);
  const int nu1 = 12 + (slice < 12);
  const int u1  = slice * 12 + (slice < 12 ? slice : 12);

  float* hib = ws + OFF_HIB;
  float* hcb = ws + OFF_HCB;
  int* flag = (int*)(ws + OFF_FLG) + group * 16;

  // ---- stage weights ONCE ----
  {
    const uint4* WAg = (const uint4*)((u32*)ws + OFF_WAG) + slice * (20 * 144);
    for (int i = tid; i < nu0 * 144; i += 512) {
      int u = i / 144, q = i - u * 144;
      WAl[u * 145 + q] = WAg[i];
    }
    const uint4* WBg = (const uint4*)((u32*)ws + OFF_WBG) + slice * (13 * 192);
    for (int i = tid; i < nu1 * 192; i += 512) {
      int u = i / 192, q = i - u * 192;
      WBl[u * 193 + q] = WBg[i];
    }
    for (int i = tid; i < 416; i += 512) {
      WC1l[i] = ws[OFF_WC1 + i];
      WC2l[i] = ws[OFF_WC1 + 416 + i];
      WCTl[i] = ws[OFF_WC1 + 832 + i];
    }
    if (slice == NSL - 1 && tid < 32) {
      int r = tid >> 1, u2 = tid & 1;
      hmloc[32 + r * 2 + u2] = h0[(size_t)(rows0 + r) * 512 + 510 + u2];   // hm(-1) -> buf 1
    }
  }
  __syncthreads();

  for (int t = 0; t < TSLEN; ++t) {
    const int cb = t & 1, pb = cb ^ 1;

    // ---- A-stage: XA rows = [x(t)(64) | hi(t-1)(306) | 0-pad(384)] fp16 ----
    {
      const float* hisrc = hib + (size_t)pb * (256 * 306);
      for (int i = tid; i < RPG * 192; i += 512) {
        int r = i / 192, j = i - r * 192;
        int k = 2 * j;
        float v0 = 0.f, v1 = 0.f;
        if (k < 64) {
          float2 xv = *(const float2*)(x + ((size_t)(rows0 + r) * TSLEN + t) * 64 + k);
          v0 = xv.x; v1 = xv.y;
        } else if (k < D0) {
          float2 hv = *(const float2*)(hisrc + (size_t)(rows0 + r) * 306 + (k - 64));
          v0 = hv.x; v1 = hv.y;
        }
        ((u32*)XA)[r * 196 + j] = packh2(v0, v1);
      }
    }
    __syncthreads();

    // ---- A-dots (lanes < nu0*16) ; C(t-1) on slice 15 wave 5 ----
    if (tid < nu0 * 16) {
      int ul = tid >> 4, r = tid & 15;
      const uint4* wrow = WAl + ul * 145;
      const uint4* xrow = XA + r * 49;
      float a0 = 0.f, a1 = 0.f, a2 = 0.f;
      #pragma unroll 8
      for (int k8 = 0; k8 < 48; ++k8) {
        uint4 xq = xrow[k8];
        dot3p(wrow[k8], wrow[48 + k8], wrow[96 + k8], xq, a0, a1, a2);
      }
      int u = u0 + ul;
      float4 b = *((const float4*)(ws + OFF_BA) + u);
      hib[(size_t)cb * (256 * 306) + (size_t)(rows0 + r) * 306 + u] = cellact3(a0, a1, a2, b);
    } else if (slice == NSL - 1 && t > 0 && tid >= 320 && tid < 384) {
      // hm(t-1) = cell2([hc(t-1), hm(t-2)])
      int l = tid - 320, r = l >> 2, u2 = (l >> 1) & 1, c = l & 1;
      const float* hcsrc = hcb + (size_t)pb * (256 * 204) + (size_t)(rows0 + r) * 204;
      float a1 = 0.f, a2 = 0.f, at = 0.f;
      int d0 = c * 104;
      #pragma unroll 4
      for (int jj = 0; jj < 104; ++jj) {
        int d = d0 + jj;
        if (d >= D2) break;
        float xv = (d < N1) ? hcsrc[d] : hmloc[cb * 32 + r * 2 + (d - N1)];
        a1 = fmaf(WC1l[u2 * 208 + d], xv, a1);
        a2 = fmaf(WC2l[u2 * 208 + d], xv, a2);
        at = fmaf(WCTl[u2 * 208 + d], xv, at);
      }
      a1 += __shfl_xor(a1, 1); a2 += __shfl_xor(a2, 1); at += __shfl_xor(at, 1);
      if (c == 0) {
        float4 b = *((const float4*)(ws + OFF_B2) + u2);
        hmloc[pb * 32 + r * 2 + u2] = cellact3(a1, a2, at, b);
      }
    }
    group_sync(flag, 32 * t + 16);

    // ---- B-stage: XB rows = [hi(t)(306) | hc(t-1)(204) | 0-pad(512)] fp16 ----
    {
      const float* hisrc = hib + (size_t)cb * (256 * 306);
      const float* hcsrc = hcb + (size_t)pb * (256 * 204);
      for (int i = tid; i < RPG * 256; i += 512) {
        int r = i >> 8, j = i & 255;
        int k = 2 * j;
        float v0 = 0.f, v1 = 0.f;
        if (k < N0) {
          float2 hv = *(const float2*)(hisrc + (size_t)(rows0 + r) * 306 + k);
          v0 = hv.x; v1 = hv.y;
        } else if (k < D1) {
          float2 hv = *(const float2*)(hcsrc + (size_t)(rows0 + r) * 204 + (k - N0));
          v0 = hv.x; v1 = hv.y;
        }
        ((u32*)XB)[r * 260 + j] = packh2(v0, v1);
      }
    }
    __syncthreads();

    // ---- B-dots (lanes < nu1*16) ----
    if (tid < nu1 * 16) {
      int ul = tid >> 4, r = tid & 15;
      const uint4* wrow = WBl + ul * 193;
      const uint4* xrow = XB + r * 65;
      float a0 = 0.f, a1 = 0.f, a2 = 0.f;
      #pragma unroll 8
      for (int k8 = 0; k8 < 64; ++k8) {
        uint4 xq = xrow[k8];
        dot3p(wrow[k8], wrow[64 + k8], wrow[128 + k8], xq, a0, a1, a2);
      }
      int u = u1 + ul;
      float4 b = *((const float4*)(ws + OFF_BB) + u);
      hcb[(size_t)cb * (256 * 204) + (size_t)(rows0 + r) * 204 + u] = cellact3(a0, a1, a2, b);
    }
    group_sync(flag, 32 * t + 32);
  }

  // ---- epilogue (slice 15 of each group) ----
  if (slice != NSL - 1) return;
  if (tid >= 320 && tid < 384) {   // hm(511) = cell2([hc(511), hm(510)])
    int l = tid - 320, r = l >> 2, u2 = (l >> 1) & 1, c = l & 1;
    const float* hcsrc = hcb + (size_t)1 * (256 * 204) + (size_t)(rows0 + r) * 204;
    float a1 = 0.f, a2 = 0.f, at = 0.f;
    int d0 = c * 104;
    for (int jj = 0; jj < 104; ++jj) {
      int d = d0 + jj;
      if (d >= D2) break;
      float xv = (d < N1) ? hcsrc[d] : hmloc[0 * 32 + r * 2 + (d - N1)];   // hm(510) in buf 0
      a1 = fmaf(WC1l[u2 * 208 + d], xv, a1);
      a2 = fmaf(WC2l[u2 * 208 + d], xv, a2);
      at = fmaf(WCTl[u2 * 208 + d], xv, at);
    }
    a1 += __shfl_xor(a1, 1); a2 += __shfl_xor(a2, 1); at += __shfl_xor(at, 1);
    if (c == 0) {
      float4 b = *((const float4*)(ws + OFF_B2) + u2);
      hmloc[32 + r * 2 + u2] = cellact3(a1, a2, at, b);   // hm(511) -> buf 1
    }
  }
  __syncthreads();

  if (tid < 32) {   // predictions
    int r = tid >> 1, o = tid & 1;
    float m0v = hmloc[32 + r * 2 + 0], m1v = hmloc[32 + r * 2 + 1];
    out[(size_t)(rows0 + r) * 2 + o] = m0v * fcw[o * 2 + 0] + m1v * fcw[o * 2 + 1] + fcb[o];
  }
  {
    const float* hisrc = hib + (size_t)1 * (256 * 306);
    const float* hcsrc = hcb + (size_t)1 * (256 * 204);
    for (int i = tid; i < RPG * 512; i += 512) {
      int r = i >> 9, c = i & 511;
      float v;
      if (c < N0)        v = hisrc[(size_t)(rows0 + r) * 306 + c];
      else if (c < 510)  v = hcsrc[(size_t)(rows0 + r) * 204 + (c - N0)];
      else               v = hmloc[32 + r * 2 + (c - 510)];
      out[512 + (size_t)(rows0 + r) * 512 + c] = v;
    }
  }
}

extern "C" void kernel_launch(void* const* d_in, const int* in_sizes, int n_in,
                              void* d_out, int out_size, void* d_ws, size_t ws_size,
                              hipStream_t stream) {
  const float* x    = (const float*)d_in[0];
  const float* h0   = (const float*)d_in[1];
  const float* f1w0 = (const float*)d_in[2];
  const float* f1b0 = (const float*)d_in[3];
  const float* f2w0 = (const float*)d_in[4];
  const float* f2b0 = (const float*)d_in[5];
  const float* taw0 = (const float*)d_in[6];
  const float* tab0 = (const float*)d_in[7];
  const float* tbw0 = (const float*)d_in[8];
  const float* tbb0 = (const float*)d_in[9];
  const int*   m0   = (const int*)d_in[10];
  const float* f1w1 = (const float*)d_in[11];
  const float* f1b1 = (const float*)d_in[12];
  const float* f2w1 = (const float*)d_in[13];
  const float* f2b1 = (const float*)d_in[14];
  const float* taw1 = (const float*)d_in[15];
  const float* tab1 = (const float*)d_in[16];
  const float* tbw1 = (const float*)d_in[17];
  const float* tbb1 = (const float*)d_in[18];
  const int*   m1   = (const int*)d_in[19];
  const float* f1w2 = (const float*)d_in[20];
  const float* f1b2 = (const float*)d_in[21];
  const float* f2w2 = (const float*)d_in[22];
  const float* f2b2 = (const float*)d_in[23];
  const float* taw2 = (const float*)d_in[24];
  const float* tab2 = (const float*)d_in[25];
  const float* tbw2 = (const float*)d_in[26];
  const float* tbb2 = (const float*)d_in[27];
  const int*   m2   = (const int*)d_in[28];
  const float* fcw  = (const float*)d_in[29];
  const float* fcb  = (const float*)d_in[30];

  float* ws  = (float*)d_ws;
  float* out = (float*)d_out;

  // prep items: 184320+159744+1248+306+204+2+78336+52224+256 = 476,640
  prep_kernel<<<1862, 256, 0, stream>>>(
      h0,
      f1w0, f2w0, taw0, tbw0, m0, f1b0, f2b0, tab0, tbb0,
      f1w1, f2w1, taw1, tbw1, m1, f1b1, f2b1, tab1, tbb1,
      f1w2, f2w2, taw2, tbw2, m2, f1b2, f2b2, tab2, tbb2,
      ws);

  static const int kShmem = 120976;   // > 80 KiB -> 1 block/CU -> 256 blocks co-resident
  hipFuncSetAttribute((const void*)lnn_main, hipFuncAttributeMaxDynamicSharedMemorySize, kShmem);
  lnn_main<<<256, 512, kShmem, stream>>>(x, h0, fcw, fcb, ws, out);
}

// Round 10
// 13974.908 us; speedup vs baseline: 2.0870x; 2.0536x over previous
//
#include <hip/hip_runtime.h>
#include <hip/hip_fp16.h>

typedef unsigned int u32;
typedef _Float16 h2v __attribute__((ext_vector_type(2)));

#define TSLEN 512
#define N0 306
#define N1 204
#define D0 370
#define D1 510
#define D2 206

// ws u32/f32 offsets (round-7 verified layout + pacing counters)
#define OFF_WA  0          // uint4[48][918]  layer-A planes (plane-major, lane-coalesced)
#define OFF_WB  176256     // uint4[48][816]  layer-B planes
#define OFF_WC1 332928     // f32[2][208]
#define OFF_WC2 333344
#define OFF_WCT 333760
#define OFF_BA  334176     // float4[306]
#define OFF_BB  335400     // float4[204]
#define OFF_B2  336216     // float4[2]
#define OFF_CTR 336224     // int[8][32]: per-XCD-cohort pacing counters (stride 128B)
// total 336480 dwords = 1.35 MB

__device__ __forceinline__ u32 packh2(float a, float b) {
  __half2 h = __floats2half2_rn(a, b);
  return __builtin_bit_cast(u32, h);
}

__device__ __forceinline__ float dot2(u32 w, u32 xx, float acc) {
  return __builtin_amdgcn_fdot2(__builtin_bit_cast(h2v, w), __builtin_bit_cast(h2v, xx), acc, false);
}

__device__ __forceinline__ float cellact3(float a1, float a2, float at, float4 b) {
  float t1 = tanhf(a1 + b.x);
  float t2 = tanhf(a2 + b.y);
  float tv = 1.f / (1.f + __expf(-(at + b.z)));   // sigmoid(tb - ta)
  return t1 * (1.f - tv) + tv * t2;
}

// 8 coalesced uint4 weight loads (stride STR uint4s) + 32 fdot2 against reg-held x.
template<int STR>
__device__ __forceinline__ float dot8(const uint4* __restrict__ wp, const uint4 (&xv)[8], float a) {
  uint4 wv[8];
  #pragma unroll
  for (int j = 0; j < 8; ++j) wv[j] = wp[j * STR];
  #pragma unroll
  for (int j = 0; j < 8; ++j) {
    a = dot2(wv[j].x, xv[j].x, a);
    a = dot2(wv[j].y, xv[j].y, a);
    a = dot2(wv[j].z, xv[j].z, a);
    a = dot2(wv[j].w, xv[j].w, a);
  }
  return a;
}

__global__ __launch_bounds__(256) void prep_kernel(
    const float* __restrict__ f1w0, const float* __restrict__ f2w0,
    const float* __restrict__ taw0, const float* __restrict__ tbw0, const int* __restrict__ m0,
    const float* __restrict__ f1b0, const float* __restrict__ f2b0,
    const float* __restrict__ tab0, const float* __restrict__ tbb0,
    const float* __restrict__ f1w1, const float* __restrict__ f2w1,
    const float* __restrict__ taw1, const float* __restrict__ tbw1, const int* __restrict__ m1,
    const float* __restrict__ f1b1, const float* __restrict__ f2b1,
    const float* __restrict__ tab1, const float* __restrict__ tbb1,
    const float* __restrict__ f1w2, const float* __restrict__ f2w2,
    const float* __restrict__ taw2, const float* __restrict__ tbw2, const int* __restrict__ m2,
    const float* __restrict__ f1b2, const float* __restrict__ f2b2,
    const float* __restrict__ tab2, const float* __restrict__ tbb2,
    float* __restrict__ ws)
{
  int j = blockIdx.x * 256 + threadIdx.x;
  u32* W = (u32*)ws;
  if (j < 176256) {                       // layer A: [plane*16+jj][u*3+s] uint4, component c
    int q4 = j >> 2, c = j & 3;
    int jq = q4 / 918, us = q4 - jq * 918;
    int u = us / 3, s = us - u * 3;
    int plane = jq >> 4, jj = jq & 15;
    int p = s * 64 + jj * 4 + c;          // k-pair index in padded 384-k space
    int k0 = 2 * p, k1 = 2 * p + 1;
    float v0 = 0.f, v1 = 0.f;
    if (k0 < D0) {
      int i = u * D0 + k0;
      v0 = (plane == 0) ? f1w0[i] * (float)m0[i]
         : (plane == 1) ? f2w0[i] * (float)m0[i]
                        : tbw0[i] - taw0[i];
    }
    if (k1 < D0) {
      int i = u * D0 + k1;
      v1 = (plane == 0) ? f1w0[i] * (float)m0[i]
         : (plane == 1) ? f2w0[i] * (float)m0[i]
                        : tbw0[i] - taw0[i];
    }
    W[OFF_WA + j] = packh2(v0, v1);
    return;
  }
  j -= 176256;
  if (j < 156672) {                       // layer B: [plane*16+jj][u*4+s]
    int q4 = j >> 2, c = j & 3;
    int jq = q4 / 816, us = q4 - jq * 816;
    int u = us >> 2, s = us & 3;
    int plane = jq >> 4, jj = jq & 15;
    int p = s * 64 + jj * 4 + c;          // padded 512-k space
    int k0 = 2 * p, k1 = 2 * p + 1;
    float v0 = 0.f, v1 = 0.f;
    if (k0 < D1) {
      int i = u * D1 + k0;
      v0 = (plane == 0) ? f1w1[i] * (float)m1[i]
         : (plane == 1) ? f2w1[i] * (float)m1[i]
                        : tbw1[i] - taw1[i];
    }
    if (k1 < D1) {
      int i = u * D1 + k1;
      v1 = (plane == 0) ? f1w1[i] * (float)m1[i]
         : (plane == 1) ? f2w1[i] * (float)m1[i]
                        : tbw1[i] - taw1[i];
    }
    W[OFF_WB + j] = packh2(v0, v1);
    return;
  }
  j -= 156672;
  if (j < 416) {                          // layer C (fp32 [u][208])
    int u = j / 208, d = j - u * 208;
    float f1 = 0.f, f2 = 0.f, td = 0.f;
    if (d < D2) { int i = u * D2 + d; float m = (float)m2[i]; f1 = f1w2[i]*m; f2 = f2w2[i]*m; td = tbw2[i]-taw2[i]; }
    ws[OFF_WC1 + j] = f1; ws[OFF_WC2 + j] = f2; ws[OFF_WCT + j] = td;
    return;
  }
  j -= 416;
  if (j < 306) { ((float4*)(ws + OFF_BA))[j] = make_float4(f1b0[j], f2b0[j], tbb0[j] - tab0[j], 0.f); return; }
  j -= 306;
  if (j < 204) { ((float4*)(ws + OFF_BB))[j] = make_float4(f1b1[j], f2b1[j], tbb1[j] - tab1[j], 0.f); return; }
  j -= 204;
  if (j < 2)   { ((float4*)(ws + OFF_B2))[j] = make_float4(f1b2[j], f2b2[j], tbb2[j] - tab2[j], 0.f); return; }
  j -= 2;
  if (j < 256) { ((int*)(ws + OFF_CTR))[j] = 0; return; }   // pacing counters
}

// One block (1024 thr) = one batch row. Weights streamed from ws (L2-shared image)
// every step via coalesced b128 loads; per-XCD cohorts phase-locked with RELAXED
// atomics (pacing only — no data shared between blocks, fail-open by design).
__global__ __launch_bounds__(1024, 1) void lnn_main(
    const float* __restrict__ x, const float* __restrict__ h0,
    const float* __restrict__ fcw, const float* __restrict__ fcb,
    const float* __restrict__ ws, int* __restrict__ ctr, float* __restrict__ out)
{
  __shared__ uint4 XA4[48];      // [x(64)|hi(306)|pad] as half2, 3 spans x 16 uint4
  __shared__ uint4 XB4[64];      // [hi(306)|hc(204)|pad], 4 spans x 16 uint4
  __shared__ float XB32[512];    // f32 copies: hi(306) | hc(204) | pad
  __shared__ float pA[918 * 3];
  __shared__ float pB[204 * 13];
  __shared__ float shm2[2];

  const int tid = threadIdx.x;
  const int row = blockIdx.x;
  int* cohort_ctr = ctr + (blockIdx.x & 7) * 32;   // bid%8 -> XCD under round-robin dispatch

  const int sA_ = tid % 3;                  // A: tid = u*3 + s, tid < 918
  const int uB = tid >> 2, sB_ = tid & 3;   // B: tid = u*4 + s, tid < 816
  const int l15 = tid - 960, u2 = l15 & 1, ch = l15 >> 1;   // wave 15: layer C

  const uint4* __restrict__ WA4 = (const uint4*)((const u32*)ws + OFF_WA);
  const uint4* __restrict__ WB4 = (const uint4*)((const u32*)ws + OFF_WB);
  const float4* BA4 = (const float4*)(ws + OFF_BA);
  const float4* BB4 = (const float4*)(ws + OFF_BB);
  const float4* B24 = (const float4*)(ws + OFF_B2);

  __half* XAh = (__half*)XA4;
  __half* XBh = (__half*)XB4;

  float4 ba = make_float4(0.f,0.f,0.f,0.f), bb = make_float4(0.f,0.f,0.f,0.f), b2 = make_float4(0.f,0.f,0.f,0.f);
  float wc1[7], wc2[7], wct[7];
  float hm0 = 0.f, hm1 = 0.f;

  if (tid < 306) ba = BA4[tid];
  if (tid < 204) bb = BB4[tid];
  if (tid >= 960) {
    #pragma unroll
    for (int j = 0; j < 7; ++j) {
      int d = ch * 7 + j;
      bool ok = d < 208;
      wc1[j] = ok ? ws[OFF_WC1 + u2 * 208 + d] : 0.f;
      wc2[j] = ok ? ws[OFF_WC2 + u2 * 208 + d] : 0.f;
      wct[j] = ok ? ws[OFF_WCT + u2 * 208 + d] : 0.f;
    }
    b2 = B24[u2];
    hm0 = h0[(size_t)row * 512 + 510];
    hm1 = h0[(size_t)row * 512 + 511];
  }

  // ---- init LDS state ----
  if (tid < 306) {
    float v = h0[(size_t)row * 512 + tid];
    XAh[64 + tid] = __float2half(v);
  }
  if (tid < 204) {
    float v = h0[(size_t)row * 512 + 306 + tid];
    XBh[306 + tid] = __float2half(v);
    XB32[306 + tid] = v;
  }
  if (tid < 14) XAh[370 + tid] = __float2half(0.f);   // pad k 370..383
  if (tid >= 14 && tid < 16) XBh[510 + (tid - 14)] = __float2half(0.f);
  __syncthreads();

  for (int t = 0; t < TSLEN; ++t) {
    // ---- phase 1: B-finish(t-1) on tid<204; x_t staging on tid 204..235 ----
    if (t > 0 && tid < 204) {
      int b = tid * 13;
      float a1 = pB[b+0] + pB[b+3] + pB[b+6] + pB[b+9];
      float a2 = pB[b+1] + pB[b+4] + pB[b+7] + pB[b+10];
      float at = pB[b+2] + pB[b+5] + pB[b+8] + pB[b+11];
      float hc = cellact3(a1, a2, at, bb);
      XB32[306 + tid] = hc;
      XBh[306 + tid] = __float2half(hc);
    } else if (tid >= 204 && tid < 236) {
      int i = tid - 204;
      float2 xv = *(const float2*)(x + ((size_t)row * TSLEN + t) * 64 + 2 * i);
      ((u32*)XA4)[i] = packh2(xv.x, xv.y);
    }
    __syncthreads();

    // ---- phase 2: A-partials (tid<918, streamed weights) + lagged layer C (wave 15) ----
    if (tid < 918) {
      const uint4* wp = WA4 + tid;
      const uint4* xs = XA4 + sA_ * 16;
      float a1 = 0.f, a2 = 0.f, at = 0.f;
      #pragma unroll
      for (int h = 0; h < 2; ++h) {
        uint4 xv[8];
        #pragma unroll
        for (int j = 0; j < 8; ++j) xv[j] = xs[h * 8 + j];
        a1 = dot8<918>(wp + (0 * 16 + h * 8) * 918, xv, a1);
        a2 = dot8<918>(wp + (1 * 16 + h * 8) * 918, xv, a2);
        at = dot8<918>(wp + (2 * 16 + h * 8) * 918, xv, at);
      }
      pA[tid * 3 + 0] = a1; pA[tid * 3 + 1] = a2; pA[tid * 3 + 2] = at;
    } else if (tid >= 960 && t > 0) {
      float a1 = 0.f, a2 = 0.f, at = 0.f;
      #pragma unroll
      for (int j = 0; j < 7; ++j) {
        int d = ch * 7 + j;
        float xv = (d < 204) ? XB32[306 + d] : (d == 204 ? hm0 : (d == 205 ? hm1 : 0.f));
        a1 = fmaf(wc1[j], xv, a1); a2 = fmaf(wc2[j], xv, a2); at = fmaf(wct[j], xv, at);
      }
      #pragma unroll
      for (int m = 2; m <= 32; m <<= 1) {
        a1 += __shfl_xor(a1, m); a2 += __shfl_xor(a2, m); at += __shfl_xor(at, m);
      }
      float hmn = cellact3(a1, a2, at, b2);
      float other = __shfl_xor(hmn, 1);
      hm0 = (u2 == 0) ? hmn : other;
      hm1 = (u2 == 0) ? other : hmn;
    }
    __syncthreads();

    // ---- phase 3: A-finish -> hi(t) ----
    if (tid < 306) {
      int b = tid * 9;
      float a1 = pA[b+0] + pA[b+3] + pA[b+6];
      float a2 = pA[b+1] + pA[b+4] + pA[b+7];
      float at = pA[b+2] + pA[b+5] + pA[b+8];
      float hi = cellact3(a1, a2, at, ba);
      XB32[tid] = hi;
      __half hh = __float2half(hi);
      XBh[tid] = hh;
      XAh[64 + tid] = hh;
    }
    __syncthreads();

    // ---- phase 4: B-partials (tid<816, streamed weights) ----
    if (tid < 816) {
      const uint4* wp = WB4 + tid;
      const uint4* xs = XB4 + sB_ * 16;
      float a1 = 0.f, a2 = 0.f, at = 0.f;
      #pragma unroll
      for (int h = 0; h < 2; ++h) {
        uint4 xv[8];
        #pragma unroll
        for (int j = 0; j < 8; ++j) xv[j] = xs[h * 8 + j];
        a1 = dot8<816>(wp + (0 * 16 + h * 8) * 816, xv, a1);
        a2 = dot8<816>(wp + (1 * 16 + h * 8) * 816, xv, a2);
        at = dot8<816>(wp + (2 * 16 + h * 8) * 816, xv, at);
      }
      pB[uB * 13 + sB_ * 3 + 0] = a1;
      pB[uB * 13 + sB_ * 3 + 1] = a2;
      pB[uB * 13 + sB_ * 3 + 2] = at;
    }
    __syncthreads();

    // ---- XCD-cohort phase-lock: RELAXED atomics, pacing only (fail-open) ----
    if (tid == 0) {
      __hip_atomic_fetch_add(cohort_ctr, 1, __ATOMIC_RELAXED, __HIP_MEMORY_SCOPE_AGENT);
      int spins = 0;
      while (__hip_atomic_load(cohort_ctr, __ATOMIC_RELAXED, __HIP_MEMORY_SCOPE_AGENT) < 32 * (t + 1)
             && ++spins < 50000)
        __builtin_amdgcn_s_sleep(2);
    }
    __syncthreads();
  }

  // ---- epilogue ----
  if (tid < 204) {   // B-finish t=511 -> hc(511)
    int b = tid * 13;
    float a1 = pB[b+0] + pB[b+3] + pB[b+6] + pB[b+9];
    float a2 = pB[b+1] + pB[b+4] + pB[b+7] + pB[b+10];
    float at = pB[b+2] + pB[b+5] + pB[b+8] + pB[b+11];
    XB32[306 + tid] = cellact3(a1, a2, at, bb);
  }
  __syncthreads();
  if (tid >= 960) {  // hm(511) from hc(511) + hm(510)
    float a1 = 0.f, a2 = 0.f, at = 0.f;
    #pragma unroll
    for (int j = 0; j < 7; ++j) {
      int d = ch * 7 + j;
      float xv = (d < 204) ? XB32[306 + d] : (d == 204 ? hm0 : (d == 205 ? hm1 : 0.f));
      a1 = fmaf(wc1[j], xv, a1); a2 = fmaf(wc2[j], xv, a2); at = fmaf(wct[j], xv, at);
    }
    #pragma unroll
    for (int m = 2; m <= 32; m <<= 1) {
      a1 += __shfl_xor(a1, m); a2 += __shfl_xor(a2, m); at += __shfl_xor(at, m);
    }
    float hmn = cellact3(a1, a2, at, b2);
    if (l15 < 2) shm2[u2] = hmn;
  }
  __syncthreads();

  if (tid < 2) {
    int o = tid;
    out[(size_t)row * 2 + o] = shm2[0] * fcw[o * 2 + 0] + shm2[1] * fcw[o * 2 + 1] + fcb[o];
  }
  if (tid < 512) {
    float v = (tid < 510) ? XB32[tid] : shm2[tid - 510];
    out[512 + (size_t)row * 512 + tid] = v;
  }
}

extern "C" void kernel_launch(void* const* d_in, const int* in_sizes, int n_in,
                              void* d_out, int out_size, void* d_ws, size_t ws_size,
                              hipStream_t stream) {
  const float* x    = (const float*)d_in[0];
  const float* h0   = (const float*)d_in[1];
  const float* f1w0 = (const float*)d_in[2];
  const float* f1b0 = (const float*)d_in[3];
  const float* f2w0 = (const float*)d_in[4];
  const float* f2b0 = (const float*)d_in[5];
  const float* taw0 = (const float*)d_in[6];
  const float* tab0 = (const float*)d_in[7];
  const float* tbw0 = (const float*)d_in[8];
  const float* tbb0 = (const float*)d_in[9];
  const int*   m0   = (const int*)d_in[10];
  const float* f1w1 = (const float*)d_in[11];
  const float* f1b1 = (const float*)d_in[12];
  const float* f2w1 = (const float*)d_in[13];
  const float* f2b1 = (const float*)d_in[14];
  const float* taw1 = (const float*)d_in[15];
  const float* tab1 = (const float*)d_in[16];
  const float* tbw1 = (const float*)d_in[17];
  const float* tbb1 = (const float*)d_in[18];
  const int*   m1   = (const int*)d_in[19];
  const float* f1w2 = (const float*)d_in[20];
  const float* f1b2 = (const float*)d_in[21];
  const float* f2w2 = (const float*)d_in[22];
  const float* f2b2 = (const float*)d_in[23];
  const float* taw2 = (const float*)d_in[24];
  const float* tab2 = (const float*)d_in[25];
  const float* tbw2 = (const float*)d_in[26];
  const float* tbb2 = (const float*)d_in[27];
  const int*   m2   = (const int*)d_in[28];
  const float* fcw  = (const float*)d_in[29];
  const float* fcb  = (const float*)d_in[30];

  float* ws  = (float*)d_ws;
  float* out = (float*)d_out;

  // prep items: 176256 + 156672 + 416 + 306 + 204 + 2 + 256 = 334,112
  prep_kernel<<<1306, 256, 0, stream>>>(
      f1w0, f2w0, taw0, tbw0, m0, f1b0, f2b0, tab0, tbb0,
      f1w1, f2w1, taw1, tbw1, m1, f1b1, f2b1, tab1, tbb1,
      f1w2, f2w2, taw2, tbw2, m2, f1b2, f2b2, tab2, tbb2,
      ws);

  lnn_main<<<256, 1024, 0, stream>>>(x, h0, fcw, fcb, ws,
                                     (int*)(ws + OFF_CTR), out);
}